// Round 13
// baseline (387.592 us; speedup 1.0000x reference)
//
#include <hip/hip_runtime.h>
#include <math.h>

#define SEQ 4096
#define DMODEL 1024
#define NHEAD 16
#define DKH 64   // head dim

typedef __attribute__((ext_vector_type(8))) short bf16x8;
typedef __attribute__((ext_vector_type(4))) float f32x4;

// fp32 -> bf16 bits, round-to-nearest-even
__device__ __forceinline__ ushort f2b(float x) {
    unsigned u = __float_as_uint(x);
    return (ushort)((u + 0x7fffu + ((u >> 16) & 1u)) >> 16);
}
// bf16 bits -> fp32
__device__ __forceinline__ float b2f(ushort u) {
    return __uint_as_float(((unsigned)u) << 16);
}

// DPP row_ror:n combine (row = 16 lanes on CDNA). VALU-speed reductions.
#define DPP_ROR_F(x, ctrl) \
    __int_as_float(__builtin_amdgcn_update_dpp(__float_as_int(x), __float_as_int(x), (ctrl), 0xf, 0xf, false))

__device__ __forceinline__ float rowmax16(float x) {
    x = fmaxf(x, DPP_ROR_F(x, 0x121));   // ror 1
    x = fmaxf(x, DPP_ROR_F(x, 0x122));   // ror 2
    x = fmaxf(x, DPP_ROR_F(x, 0x124));   // ror 4
    x = fmaxf(x, DPP_ROR_F(x, 0x128));   // ror 8
    return x;
}
__device__ __forceinline__ float rowsum16(float x) {
    x += DPP_ROR_F(x, 0x121);
    x += DPP_ROR_F(x, 0x122);
    x += DPP_ROR_F(x, 0x124);
    x += DPP_ROR_F(x, 0x128);
    return x;
}

// ---------------------------------------------------------------------------
// Convert x (4096x1024) and the four 1024x1024 weights to bf16, one launch.
// ---------------------------------------------------------------------------
__global__ __launch_bounds__(256)
void conv_bf16(const float* __restrict__ x,  const float* __restrict__ wq,
               const float* __restrict__ wk, const float* __restrict__ wv,
               const float* __restrict__ wo,
               ushort* __restrict__ xb,  ushort* __restrict__ wqb,
               ushort* __restrict__ wkb, ushort* __restrict__ wvb,
               ushort* __restrict__ wob) {
    const int b = blockIdx.x;
    const float* src; ushort* dst; int idx;
    if (b < 4096) {
        src = x; dst = xb; idx = b * 256 + threadIdx.x;
    } else {
        int t = b - 4096;
        int which = t >> 10;            // 0..3
        idx = (t & 1023) * 256 + threadIdx.x;
        if      (which == 0) { src = wq; dst = wqb; }
        else if (which == 1) { src = wk; dst = wkb; }
        else if (which == 2) { src = wv; dst = wvb; }
        else                 { src = wo; dst = wob; }
    }
    float4 f = ((const float4*)src)[idx];
    ushort4 o;
    o.x = f2b(f.x); o.y = f2b(f.y); o.z = f2b(f.z); o.w = f2b(f.w);
    ((ushort4*)dst)[idx] = o;
}

// ---------------------------------------------------------------------------
// bf16 MFMA GEMM: C[M][N] = sum_k A[m][k] * B[n][k]  (C = A.B^T), fp32 acc.
// Tile 128x128, BK=32, 256 threads = 4 waves (2x2), each wave 64x64 out.
// (unchanged from round-8/10 passing version)
// ---------------------------------------------------------------------------
#define GSTR 40

template<bool OUT_BF16>
__global__ __launch_bounds__(256)
void gemm_bf16(const ushort* __restrict__ A, const ushort* __restrict__ B,
               void* __restrict__ Cv, int M, int N, int K) {
    __shared__ __attribute__((aligned(16))) ushort As[128 * GSTR];
    __shared__ __attribute__((aligned(16))) ushort Bs[128 * GSTR];

    const int tid  = threadIdx.x;
    const int lane = tid & 63;
    const int w    = tid >> 6;
    const int wr   = w >> 1, wc = w & 1;
    const int lrow = lane & 15, lgrp = lane >> 4;
    const int m0 = blockIdx.y * 128;
    const int n0 = blockIdx.x * 128;

    const int srow = tid >> 2;            // 0..63
    const int skc  = (tid & 3) * 8;       // 0,8,16,24
    const ushort* Ap0 = A + (size_t)(m0 + srow) * K + skc;
    const ushort* Ap1 = Ap0 + (size_t)64 * K;
    const ushort* Bp0 = B + (size_t)(n0 + srow) * K + skc;
    const ushort* Bp1 = Bp0 + (size_t)64 * K;
    ushort* sA0 = &As[srow * GSTR + skc];
    ushort* sA1 = &As[(srow + 64) * GSTR + skc];
    ushort* sB0 = &Bs[srow * GSTR + skc];
    ushort* sB1 = &Bs[(srow + 64) * GSTR + skc];

    f32x4 acc[4][4];
#pragma unroll
    for (int i = 0; i < 4; i++)
#pragma unroll
        for (int j = 0; j < 4; j++) acc[i][j] = (f32x4){0.f, 0.f, 0.f, 0.f};

    bf16x8 ra0 = *(const bf16x8*)(Ap0);
    bf16x8 ra1 = *(const bf16x8*)(Ap1);
    bf16x8 rb0 = *(const bf16x8*)(Bp0);
    bf16x8 rb1 = *(const bf16x8*)(Bp1);

    const int NT = K >> 5;   // BK=32
    for (int kt = 0; kt < NT; kt++) {
        __syncthreads();
        *(bf16x8*)sA0 = ra0;  *(bf16x8*)sA1 = ra1;
        *(bf16x8*)sB0 = rb0;  *(bf16x8*)sB1 = rb1;
        __syncthreads();

        if (kt + 1 < NT) {
            const int ko = (kt + 1) * 32;
            ra0 = *(const bf16x8*)(Ap0 + ko);
            ra1 = *(const bf16x8*)(Ap1 + ko);
            rb0 = *(const bf16x8*)(Bp0 + ko);
            rb1 = *(const bf16x8*)(Bp1 + ko);
        }

        bf16x8 af[4], bfr[4];
#pragma unroll
        for (int i = 0; i < 4; i++)
            af[i] = *(const bf16x8*)&As[(wr * 64 + i * 16 + lrow) * GSTR + lgrp * 8];
#pragma unroll
        for (int j = 0; j < 4; j++)
            bfr[j] = *(const bf16x8*)&Bs[(wc * 64 + j * 16 + lrow) * GSTR + lgrp * 8];
#pragma unroll
        for (int i = 0; i < 4; i++)
#pragma unroll
            for (int j = 0; j < 4; j++)
                acc[i][j] = __builtin_amdgcn_mfma_f32_16x16x32_bf16(af[i], bfr[j], acc[i][j], 0, 0, 0);
    }

#pragma unroll
    for (int i = 0; i < 4; i++) {
#pragma unroll
        for (int j = 0; j < 4; j++) {
#pragma unroll
            for (int r = 0; r < 4; r++) {
                const size_t row = m0 + wr * 64 + i * 16 + lgrp * 4 + r;
                const size_t col = n0 + wc * 64 + j * 16 + lrow;
                if constexpr (OUT_BF16)
                    ((ushort*)Cv)[row * N + col] = f2b(acc[i][j][r]);
                else
                    ((float*)Cv)[row * N + col] = acc[i][j][r];
            }
        }
    }
}

// ---------------------------------------------------------------------------
// RoPE in-place on bf16 q and k (interleaved pairs per head).
// ---------------------------------------------------------------------------
__global__ __launch_bounds__(256)
void rope_bf16(ushort* __restrict__ q, ushort* __restrict__ k) {
    int idx = blockIdx.x * 256 + threadIdx.x;      // over SEQ * 512 pairs
    if (idx >= SEQ * (DMODEL / 2)) return;
    int s  = idx >> 9;
    int j  = idx & 511;
    int hh = j >> 5;
    int i  = j & 31;
    const float LOG1E4_OVER32 = 0.28782313662425572f;   // ln(10000)/32
    float freq = __expf(-(float)i * LOG1E4_OVER32);
    float ang  = (float)s * freq;
    float c, sn;
    __sincosf(ang, &sn, &c);
    size_t base = (size_t)s * DMODEL + hh * DKH + 2 * i;
    float e = b2f(q[base]), o_ = b2f(q[base + 1]);
    q[base]     = f2b(e * c - o_ * sn);
    q[base + 1] = f2b(e * sn + o_ * c);
    e = b2f(k[base]); o_ = b2f(k[base + 1]);
    k[base]     = f2b(e * c - o_ * sn);
    k[base + 1] = f2b(e * sn + o_ * c);
}

// ---------------------------------------------------------------------------
// Causal flash attention, bf16 in/out, MFMA 16x16x32, fp32 accumulate.
// Round-11 structure: 512 threads = 8 waves = 2 wave-GROUPS of 4.
//  * Group g processes K-tiles kt ≡ g (mod 2) into group-private Ks/Vs[g]
//    -> longest block's serial chain halves (64 -> 32 tiles).
//    Both groups run ceil((ktmax+1)/2) iterations with IDENTICAL barrier
//    counts (inactive iterations still hit both __syncthreads).
//  * End merge through LDS: group 1 publishes (m, l, acc); group 0 combines
//    with exp2 weights and stores O. Inactive group-1 (qi=0) degenerates to
//    e1 = exp2(-inf) = 0 -- exact.
//  * Softmax in exp2 domain: 0.125*log2(e) folded into S scale (identical
//    result, one v_exp per p).
//  * Defer-rescale: skip alpha/rescale when no row max grew (__any, uniform).
//  * s_setprio(1) around MFMA clusters (T5).
// Carried: V^T XOR-swizzle, DPP reductions, reg-staged async prefetch, LPT.
// ---------------------------------------------------------------------------
#define LSTR 72
#define SCALE2 0.18033688011112042f   // 0.125 * log2(e)

__global__ __launch_bounds__(512)
void attn_mfma(const ushort* __restrict__ Q, const ushort* __restrict__ K,
               const ushort* __restrict__ V, ushort* __restrict__ O) {
    __shared__ __attribute__((aligned(16))) ushort Ks[2][64 * LSTR];
    __shared__ __attribute__((aligned(16))) ushort Vs[2][64 * LSTR];   // [d][key^swz]
    __shared__ __attribute__((aligned(16))) ushort Ps[8][16 * LSTR];

    const int tid  = threadIdx.x;
    const int w    = tid >> 6;        // 0..7
    const int g    = w >> 2;          // wave-group 0/1
    const int wg   = w & 3;           // wave within group
    const int lane = tid & 63;
    const int lrow = lane & 15;
    const int lgrp = lane >> 4;
    const int h    = blockIdx.y;
    const int qi   = (int)gridDim.x - 1 - (int)blockIdx.x;   // LPT: big blocks first
    const int qbase = qi * 64;

    // ---- Q fragments (both groups load the same 16 rows for their wg) ----
    const int qr = qbase + wg * 16 + lrow;
    const ushort* qp = Q + (size_t)qr * DMODEL + h * DKH + lgrp * 8;
    bf16x8 qfrag[2];
    qfrag[0] = *(const bf16x8*)(qp);
    qfrag[1] = *(const bf16x8*)(qp + 32);

    f32x4 o_acc[4];
#pragma unroll
    for (int t = 0; t < 4; t++) o_acc[t] = (f32x4){0.f, 0.f, 0.f, 0.f};
    float m_r[4], l_r[4];
#pragma unroll
    for (int r = 0; r < 4; r++) { m_r[r] = -INFINITY; l_r[r] = 0.f; }

    // staging geometry (group-local 256 threads): row (key) = tg>>3, col (d) = (tg&7)*8
    const int tg   = tid & 255;
    const int row0 = tg >> 3;          // 0..31
    const int col0 = (tg & 7) * 8;     // 0..56
    const ushort* Kp = K + (size_t)h * DKH;
    const ushort* Vp = V + (size_t)h * DKH;

    const int ktmax = qi;
    const int nIter = (ktmax + 2) >> 1;   // ceil((ktmax+1)/2)

    bf16x8 rk[2], rv[2];
    {   // prefetch this group's first tile (clamped address; unused if inactive)
        const int kt0 = (g <= ktmax) ? g : ktmax;
        const size_t nb = (size_t)kt0 * 64 * DMODEL;
#pragma unroll
        for (int cc = 0; cc < 2; cc++) {
            const int row = row0 + cc * 32;
            rk[cc] = *(const bf16x8*)(Kp + nb + (size_t)row * DMODEL + col0);
            rv[cc] = *(const bf16x8*)(Vp + nb + (size_t)row * DMODEL + col0);
        }
    }

    for (int it = 0; it < nIter; it++) {
        const int kt = 2 * it + g;
        const bool active = (kt <= ktmax);
        const int kbase = kt * 64;

        __syncthreads();   // group's previous tile compute done before overwrite
        if (active) {
#pragma unroll
            for (int cc = 0; cc < 2; cc++) {
                const int row = row0 + cc * 32;
                *(bf16x8*)&Ks[g][row * LSTR + col0] = rk[cc];
                const int vrow = row ^ (col0 & 56);   // XOR-swizzle
#pragma unroll
                for (int jj = 0; jj < 8; jj++)
                    Vs[g][(col0 + jj) * LSTR + vrow] = (ushort)rv[cc][jj];
            }
        }
        __syncthreads();

        if (!active) continue;   // still executed both barriers this iteration

        // ---- prefetch this group's next tile (kt+2), clamped ----
        {
            const int ktn = (kt + 2 <= ktmax) ? kt + 2 : ktmax;
            const size_t nb = (size_t)ktn * 64 * DMODEL;
#pragma unroll
            for (int cc = 0; cc < 2; cc++) {
                const int row = row0 + cc * 32;
                rk[cc] = *(const bf16x8*)(Kp + nb + (size_t)row * DMODEL + col0);
                rv[cc] = *(const bf16x8*)(Vp + nb + (size_t)row * DMODEL + col0);
            }
        }

        // ---- QK^T: S[16 q][64 keys] per wave ----
        f32x4 s[4];
        __builtin_amdgcn_s_setprio(1);
#pragma unroll
        for (int n = 0; n < 4; n++) {
            f32x4 acc = (f32x4){0.f, 0.f, 0.f, 0.f};
#pragma unroll
            for (int ks = 0; ks < 2; ks++) {
                bf16x8 kf = *(const bf16x8*)&Ks[g][(n * 16 + lrow) * LSTR + lgrp * 8 + ks * 32];
                acc = __builtin_amdgcn_mfma_f32_16x16x32_bf16(qfrag[ks], kf, acc, 0, 0, 0);
            }
            s[n] = acc;
        }
        __builtin_amdgcn_s_setprio(0);

        // ---- scale into exp2 domain + causal mask ----
        const int myq = qbase + wg * 16 + lgrp * 4;
#pragma unroll
        for (int n = 0; n < 4; n++) {
            const int key = kbase + n * 16 + lrow;
#pragma unroll
            for (int r = 0; r < 4; r++)
                s[n][r] = (key > myq + r) ? -INFINITY : s[n][r] * SCALE2;
        }

        // ---- online softmax (exp2 domain); DPP row-reduce; defer-rescale ----
        float rmax[4];
#pragma unroll
        for (int r = 0; r < 4; r++) {
            float t0 = fmaxf(fmaxf(s[0][r], s[1][r]), fmaxf(s[2][r], s[3][r]));
            rmax[r] = rowmax16(t0);
        }
        bool grew = false;
#pragma unroll
        for (int r = 0; r < 4; r++) grew = grew || (rmax[r] > m_r[r]);
        if (__any((int)grew)) {
#pragma unroll
            for (int r = 0; r < 4; r++) {
                float mnew = fmaxf(m_r[r], rmax[r]);
                float al = exp2f(m_r[r] - mnew);   // exp2(-inf)=0 on first tile
                m_r[r] = mnew;
                l_r[r] *= al;
#pragma unroll
                for (int t = 0; t < 4; t++) o_acc[t][r] *= al;
            }
        }

        float psum[4] = {0.f, 0.f, 0.f, 0.f};
#pragma unroll
        for (int n = 0; n < 4; n++) {
#pragma unroll
            for (int r = 0; r < 4; r++) {
                float p = exp2f(s[n][r] - m_r[r]);   // masked: exp2(-inf)=0
                psum[r] += p;
                Ps[w][(lgrp * 4 + r) * LSTR + n * 16 + lrow] = f2b(p);
            }
        }
#pragma unroll
        for (int r = 0; r < 4; r++)
            l_r[r] += rowsum16(psum[r]);

        // ---- PV: O += P * V   (P wave-private, V^T swizzled) ----
        __builtin_amdgcn_s_setprio(1);
#pragma unroll
        for (int ks = 0; ks < 2; ks++) {
            bf16x8 pa = *(const bf16x8*)&Ps[w][lrow * LSTR + lgrp * 8 + ks * 32];
#pragma unroll
            for (int t = 0; t < 4; t++) {
                const int xr = (2 * t + (lrow >> 3)) << 3;   // (d>>3)<<3, d = t*16+lrow
                bf16x8 vb = *(const bf16x8*)&Vs[g][(t * 16 + lrow) * LSTR + ((lgrp * 8 + ks * 32) ^ xr)];
                o_acc[t] = __builtin_amdgcn_mfma_f32_16x16x32_bf16(pa, vb, o_acc[t], 0, 0, 0);
            }
        }
        __builtin_amdgcn_s_setprio(0);
    }

    // ---- merge the two groups' partials through LDS ----
    float* abuf  = (float*)&Ks[0][0];   // [wg][lane][16] acc      (16 KB)
    float* mlbuf = (float*)&Vs[0][0];   // [wg][lane][8]  m[4],l[4] (8 KB)
    __syncthreads();                    // all tile compute done
    if (g == 1) {
        float* a  = abuf  + ((size_t)wg * 64 + lane) * 16;
        float* ml = mlbuf + ((size_t)wg * 64 + lane) * 8;
#pragma unroll
        for (int t = 0; t < 4; t++)
#pragma unroll
            for (int r = 0; r < 4; r++) a[t * 4 + r] = o_acc[t][r];
#pragma unroll
        for (int r = 0; r < 4; r++) { ml[r] = m_r[r]; ml[4 + r] = l_r[r]; }
    }
    __syncthreads();
    if (g == 0) {
        const float* a  = abuf  + ((size_t)wg * 64 + lane) * 16;
        const float* ml = mlbuf + ((size_t)wg * 64 + lane) * 8;
        float e0[4], e1[4], invl[4];
#pragma unroll
        for (int r = 0; r < 4; r++) {
            float m1 = ml[r], l1 = ml[4 + r];
            float ms = fmaxf(m_r[r], m1);
            e0[r] = exp2f(m_r[r] - ms);
            e1[r] = exp2f(m1 - ms);      // qi=0: m1=-inf -> e1=0 (exact)
            invl[r] = 1.0f / (l_r[r] * e0[r] + l1 * e1[r]);
        }
        ushort* op = O + (size_t)(qbase + wg * 16) * DMODEL + h * DKH;
#pragma unroll
        for (int t = 0; t < 4; t++)
#pragma unroll
            for (int r = 0; r < 4; r++) {
                float v = (o_acc[t][r] * e0[r] + a[t * 4 + r] * e1[r]) * invl[r];
                op[(size_t)(lgrp * 4 + r) * DMODEL + t * 16 + lrow] = f2b(v);
            }
    }
}

// ---------------------------------------------------------------------------
extern "C" void kernel_launch(void* const* d_in, const int* in_sizes, int n_in,
                              void* d_out, int out_size, void* d_ws, size_t ws_size,
                              hipStream_t stream) {
    const float* x  = (const float*)d_in[0];
    const float* Wq = (const float*)d_in[1];
    const float* Wk = (const float*)d_in[2];
    const float* Wv = (const float*)d_in[3];
    const float* Wo = (const float*)d_in[4];
    float* out = (float*)d_out;

    const size_t NM = (size_t)SEQ * DMODEL;      // 4 M elems
    const size_t NW = (size_t)DMODEL * DMODEL;   // 1 M elems
    ushort* qb  = (ushort*)d_ws;
    ushort* kb  = qb + NM;
    ushort* vb  = kb + NM;
    ushort* ob  = vb + NM;
    ushort* xb  = ob + NM;
    ushort* wqb = xb + NM;
    ushort* wkb = wqb + NW;
    ushort* wvb = wkb + NW;
    ushort* wob = wvb + NW;   // total 48 MB

    conv_bf16<<<8192, 256, 0, stream>>>(x, Wq, Wk, Wv, Wo, xb, wqb, wkb, wvb, wob);

    dim3 ggrid(DMODEL / 128, SEQ / 128);   // (8, 32)
    gemm_bf16<true><<<ggrid, 256, 0, stream>>>(xb, wqb, qb, SEQ, DMODEL, DMODEL);
    gemm_bf16<true><<<ggrid, 256, 0, stream>>>(xb, wkb, kb, SEQ, DMODEL, DMODEL);
    gemm_bf16<true><<<ggrid, 256, 0, stream>>>(xb, wvb, vb, SEQ, DMODEL, DMODEL);

    rope_bf16<<<SEQ * (DMODEL / 2) / 256, 256, 0, stream>>>(qb, kb);

    attn_mfma<<<dim3(SEQ / 64, NHEAD), 512, 0, stream>>>(qb, kb, vb, ob);

    gemm_bf16<false><<<ggrid, 256, 0, stream>>>(ob, wob, out, SEQ, DMODEL, DMODEL);
}

// Round 14
// 328.152 us; speedup vs baseline: 1.1811x; 1.1811x over previous
//
#include <hip/hip_runtime.h>
#include <math.h>

#define SEQ 4096
#define DMODEL 1024
#define NHEAD 16
#define DKH 64   // head dim

typedef __attribute__((ext_vector_type(8))) short bf16x8;
typedef __attribute__((ext_vector_type(4))) float f32x4;

// fp32 -> bf16 bits, round-to-nearest-even
__device__ __forceinline__ ushort f2b(float x) {
    unsigned u = __float_as_uint(x);
    return (ushort)((u + 0x7fffu + ((u >> 16) & 1u)) >> 16);
}
// bf16 bits -> fp32
__device__ __forceinline__ float b2f(ushort u) {
    return __uint_as_float(((unsigned)u) << 16);
}

// DPP row_ror:n combine (row = 16 lanes on CDNA). VALU-speed reductions.
#define DPP_ROR_F(x, ctrl) \
    __int_as_float(__builtin_amdgcn_update_dpp(__float_as_int(x), __float_as_int(x), (ctrl), 0xf, 0xf, false))

__device__ __forceinline__ float rowmax16(float x) {
    x = fmaxf(x, DPP_ROR_F(x, 0x121));   // ror 1
    x = fmaxf(x, DPP_ROR_F(x, 0x122));   // ror 2
    x = fmaxf(x, DPP_ROR_F(x, 0x124));   // ror 4
    x = fmaxf(x, DPP_ROR_F(x, 0x128));   // ror 8
    return x;
}

// ---------------------------------------------------------------------------
// Convert x (4096x1024) and the four 1024x1024 weights to bf16, one launch.
// ---------------------------------------------------------------------------
__global__ __launch_bounds__(256)
void conv_bf16(const float* __restrict__ x,  const float* __restrict__ wq,
               const float* __restrict__ wk, const float* __restrict__ wv,
               const float* __restrict__ wo,
               ushort* __restrict__ xb,  ushort* __restrict__ wqb,
               ushort* __restrict__ wkb, ushort* __restrict__ wvb,
               ushort* __restrict__ wob) {
    const int b = blockIdx.x;
    const float* src; ushort* dst; int idx;
    if (b < 4096) {
        src = x; dst = xb; idx = b * 256 + threadIdx.x;
    } else {
        int t = b - 4096;
        int which = t >> 10;            // 0..3
        idx = (t & 1023) * 256 + threadIdx.x;
        if      (which == 0) { src = wq; dst = wqb; }
        else if (which == 1) { src = wk; dst = wkb; }
        else if (which == 2) { src = wv; dst = wvb; }
        else                 { src = wo; dst = wob; }
    }
    float4 f = ((const float4*)src)[idx];
    ushort4 o;
    o.x = f2b(f.x); o.y = f2b(f.y); o.z = f2b(f.z); o.w = f2b(f.w);
    ((ushort4*)dst)[idx] = o;
}

// ---------------------------------------------------------------------------
// bf16 MFMA GEMM: C[M][N] = sum_k A[m][k] * B[n][k]  (C = A.B^T), fp32 acc.
// Tile 128x128, BK=32, 256 threads = 4 waves (2x2), each wave 64x64 out.
// MODE 0: fp32 C, row-major [M][N].
// MODE 1: bf16 C, row-major [M][N].
// MODE 2: bf16 QKV-split: B is the contiguous [3072][1024] {Wq;Wk;Wv} stack,
//         C base is qb; matrix index = n0>>10 selects q/k/v (each [4096][1024],
//         contiguous in ws). 1024%128==0 so each block maps to ONE matrix.
// ---------------------------------------------------------------------------
#define GSTR 40

template<int MODE>
__global__ __launch_bounds__(256)
void gemm_bf16(const ushort* __restrict__ A, const ushort* __restrict__ B,
               void* __restrict__ Cv, int M, int N, int K) {
    __shared__ __attribute__((aligned(16))) ushort As[128 * GSTR];
    __shared__ __attribute__((aligned(16))) ushort Bs[128 * GSTR];

    const int tid  = threadIdx.x;
    const int lane = tid & 63;
    const int w    = tid >> 6;
    const int wr   = w >> 1, wc = w & 1;
    const int lrow = lane & 15, lgrp = lane >> 4;
    const int m0 = blockIdx.y * 128;
    const int n0 = blockIdx.x * 128;

    const int srow = tid >> 2;            // 0..63
    const int skc  = (tid & 3) * 8;       // 0,8,16,24
    const ushort* Ap0 = A + (size_t)(m0 + srow) * K + skc;
    const ushort* Ap1 = Ap0 + (size_t)64 * K;
    const ushort* Bp0 = B + (size_t)(n0 + srow) * K + skc;
    const ushort* Bp1 = Bp0 + (size_t)64 * K;
    ushort* sA0 = &As[srow * GSTR + skc];
    ushort* sA1 = &As[(srow + 64) * GSTR + skc];
    ushort* sB0 = &Bs[srow * GSTR + skc];
    ushort* sB1 = &Bs[(srow + 64) * GSTR + skc];

    f32x4 acc[4][4];
#pragma unroll
    for (int i = 0; i < 4; i++)
#pragma unroll
        for (int j = 0; j < 4; j++) acc[i][j] = (f32x4){0.f, 0.f, 0.f, 0.f};

    bf16x8 ra0 = *(const bf16x8*)(Ap0);
    bf16x8 ra1 = *(const bf16x8*)(Ap1);
    bf16x8 rb0 = *(const bf16x8*)(Bp0);
    bf16x8 rb1 = *(const bf16x8*)(Bp1);

    const int NT = K >> 5;   // BK=32
    for (int kt = 0; kt < NT; kt++) {
        __syncthreads();
        *(bf16x8*)sA0 = ra0;  *(bf16x8*)sA1 = ra1;
        *(bf16x8*)sB0 = rb0;  *(bf16x8*)sB1 = rb1;
        __syncthreads();

        if (kt + 1 < NT) {
            const int ko = (kt + 1) * 32;
            ra0 = *(const bf16x8*)(Ap0 + ko);
            ra1 = *(const bf16x8*)(Ap1 + ko);
            rb0 = *(const bf16x8*)(Bp0 + ko);
            rb1 = *(const bf16x8*)(Bp1 + ko);
        }

        bf16x8 af[4], bfr[4];
#pragma unroll
        for (int i = 0; i < 4; i++)
            af[i] = *(const bf16x8*)&As[(wr * 64 + i * 16 + lrow) * GSTR + lgrp * 8];
#pragma unroll
        for (int j = 0; j < 4; j++)
            bfr[j] = *(const bf16x8*)&Bs[(wc * 64 + j * 16 + lrow) * GSTR + lgrp * 8];
#pragma unroll
        for (int i = 0; i < 4; i++)
#pragma unroll
            for (int j = 0; j < 4; j++)
                acc[i][j] = __builtin_amdgcn_mfma_f32_16x16x32_bf16(af[i], bfr[j], acc[i][j], 0, 0, 0);
    }

    // epilogue: C/D layout col=lane&15, row=lgrp*4+reg
#pragma unroll
    for (int i = 0; i < 4; i++) {
#pragma unroll
        for (int j = 0; j < 4; j++) {
#pragma unroll
            for (int r = 0; r < 4; r++) {
                const size_t row = m0 + wr * 64 + i * 16 + lgrp * 4 + r;
                if constexpr (MODE == 2) {
                    ushort* dst = (ushort*)Cv + (size_t)(n0 >> 10) * ((size_t)SEQ * DMODEL);
                    const size_t col = (n0 & 1023) + wc * 64 + j * 16 + lrow;
                    dst[row * DMODEL + col] = f2b(acc[i][j][r]);
                } else {
                    const size_t col = n0 + wc * 64 + j * 16 + lrow;
                    if constexpr (MODE == 1)
                        ((ushort*)Cv)[row * N + col] = f2b(acc[i][j][r]);
                    else
                        ((float*)Cv)[row * N + col] = acc[i][j][r];
                }
            }
        }
    }
}

// ---------------------------------------------------------------------------
// RoPE in-place on bf16 q and k (interleaved pairs per head).
// ---------------------------------------------------------------------------
__global__ __launch_bounds__(256)
void rope_bf16(ushort* __restrict__ q, ushort* __restrict__ k) {
    int idx = blockIdx.x * 256 + threadIdx.x;      // over SEQ * 512 pairs
    if (idx >= SEQ * (DMODEL / 2)) return;
    int s  = idx >> 9;
    int j  = idx & 511;
    int hh = j >> 5;
    int i  = j & 31;
    const float LOG1E4_OVER32 = 0.28782313662425572f;   // ln(10000)/32
    float freq = __expf(-(float)i * LOG1E4_OVER32);
    float ang  = (float)s * freq;
    float c, sn;
    __sincosf(ang, &sn, &c);
    size_t base = (size_t)s * DMODEL + hh * DKH + 2 * i;
    float e = b2f(q[base]), o_ = b2f(q[base + 1]);
    q[base]     = f2b(e * c - o_ * sn);
    q[base + 1] = f2b(e * sn + o_ * c);
    e = b2f(k[base]); o_ = b2f(k[base + 1]);
    k[base]     = f2b(e * c - o_ * sn);
    k[base + 1] = f2b(e * sn + o_ * c);
}

// ---------------------------------------------------------------------------
// Causal flash attention, bf16 in/out, MFMA 16x16x32, fp32 accumulate.
// Round-14: REVERT to the 4-wave/256-thread round-10 structure (measured 218,
// 20 waves/CU) -- round-13's split-K A/B showed the kernel is per-CU
// THROUGHPUT-bound (VALU), not chain-bound. VALU cuts this round:
//  * Row-sum via ones-MFMA: acc_l = mfma(P, ones, acc_l) -- D[q][*]=sum_k P;
//    lane/reg layout identical to l_r. Deletes 16 adds + 16-DPP chain/tile,
//    runs on the idle MFMA pipe. acc_l rescaled alongside o_acc.
//  * Unmasked fast path: kt < ktmax => kbase+63 < qbase => no masking needed
//    (16 cndmask saved on all but the diagonal tile). Wave-uniform branch.
// Carried: exp2-domain softmax, defer-rescale, DPP rowmax, V^T XOR-swizzle,
// reg-staged async prefetch, LPT, setprio around MFMA clusters.
// ---------------------------------------------------------------------------
#define LSTR 72
#define SCALE2 0.18033688011112042f   // 0.125 * log2(e)

__global__ __launch_bounds__(256)
void attn_mfma(const ushort* __restrict__ Q, const ushort* __restrict__ K,
               const ushort* __restrict__ V, ushort* __restrict__ O) {
    __shared__ __attribute__((aligned(16))) ushort Ks[64 * LSTR];
    __shared__ __attribute__((aligned(16))) ushort Vs[64 * LSTR];   // [d][key^swz]
    __shared__ __attribute__((aligned(16))) ushort Ps[4][16 * LSTR];

    const int tid  = threadIdx.x;
    const int w    = tid >> 6;
    const int lane = tid & 63;
    const int lrow = lane & 15;
    const int lgrp = lane >> 4;
    const int h    = blockIdx.y;
    const int qi   = (int)gridDim.x - 1 - (int)blockIdx.x;   // LPT: big blocks first
    const int qbase = qi * 64;

    // ---- Q fragments: direct bf16 16B loads ----
    const int qr = qbase + w * 16 + lrow;
    const ushort* qp = Q + (size_t)qr * DMODEL + h * DKH + lgrp * 8;
    bf16x8 qfrag[2];
    qfrag[0] = *(const bf16x8*)(qp);
    qfrag[1] = *(const bf16x8*)(qp + 32);

    // ones fragment for the row-sum MFMA (bf16 1.0 = 0x3F80)
    bf16x8 ones;
#pragma unroll
    for (int j = 0; j < 8; j++) ones[j] = (short)0x3F80;

    f32x4 o_acc[4];
#pragma unroll
    for (int t = 0; t < 4; t++) o_acc[t] = (f32x4){0.f, 0.f, 0.f, 0.f};
    f32x4 acc_l = (f32x4){0.f, 0.f, 0.f, 0.f};
    float m_r[4];
#pragma unroll
    for (int r = 0; r < 4; r++) m_r[r] = -INFINITY;

    // staging geometry: chunk c = tid + cc*256; row (key) = c>>3, col (d) = (c&7)*8
    const int row0 = tid >> 3;          // 0..31
    const int col0 = (tid & 7) * 8;     // 0..56
    const ushort* Kp = K + (size_t)h * DKH;
    const ushort* Vp = V + (size_t)h * DKH;

    const int ktmax = qi;
    bf16x8 rk[2], rv[2];
    // prefetch tile 0
#pragma unroll
    for (int cc = 0; cc < 2; cc++) {
        const int row = row0 + cc * 32;
        rk[cc] = *(const bf16x8*)(Kp + (size_t)row * DMODEL + col0);
        rv[cc] = *(const bf16x8*)(Vp + (size_t)row * DMODEL + col0);
    }

    for (int kt = 0; kt <= ktmax; kt++) {
        const int kbase = kt * 64;
        __syncthreads();   // previous tile's compute done before overwrite
        // ---- write staged registers to LDS ----
#pragma unroll
        for (int cc = 0; cc < 2; cc++) {
            const int row = row0 + cc * 32;
            *(bf16x8*)&Ks[row * LSTR + col0] = rk[cc];
            const int vrow = row ^ (col0 & 56);   // XOR-swizzle: (d>>3)<<3 == col0&56
#pragma unroll
            for (int jj = 0; jj < 8; jj++)
                Vs[(col0 + jj) * LSTR + vrow] = (ushort)rv[cc][jj];
        }
        __syncthreads();

        // ---- prefetch next tile (latency hides under compute below) ----
        if (kt < ktmax) {
            const size_t nb = (size_t)(kbase + 64) * DMODEL;
#pragma unroll
            for (int cc = 0; cc < 2; cc++) {
                const int row = row0 + cc * 32;
                rk[cc] = *(const bf16x8*)(Kp + nb + (size_t)row * DMODEL + col0);
                rv[cc] = *(const bf16x8*)(Vp + nb + (size_t)row * DMODEL + col0);
            }
        }

        // ---- QK^T: S[16 q][64 keys] per wave ----
        f32x4 s[4];
        __builtin_amdgcn_s_setprio(1);
#pragma unroll
        for (int n = 0; n < 4; n++) {
            f32x4 acc = (f32x4){0.f, 0.f, 0.f, 0.f};
#pragma unroll
            for (int ks = 0; ks < 2; ks++) {
                bf16x8 kf = *(const bf16x8*)&Ks[(n * 16 + lrow) * LSTR + lgrp * 8 + ks * 32];
                acc = __builtin_amdgcn_mfma_f32_16x16x32_bf16(qfrag[ks], kf, acc, 0, 0, 0);
            }
            s[n] = acc;
        }
        __builtin_amdgcn_s_setprio(0);

        // ---- scale into exp2 domain; mask ONLY on the diagonal tile ----
        if (kt == ktmax) {
            const int myq = qbase + w * 16 + lgrp * 4;
#pragma unroll
            for (int n = 0; n < 4; n++) {
                const int key = kbase + n * 16 + lrow;
#pragma unroll
                for (int r = 0; r < 4; r++)
                    s[n][r] = (key > myq + r) ? -INFINITY : s[n][r] * SCALE2;
            }
        } else {
#pragma unroll
            for (int n = 0; n < 4; n++)
#pragma unroll
                for (int r = 0; r < 4; r++) s[n][r] *= SCALE2;
        }

        // ---- online softmax (exp2 domain); DPP rowmax; defer-rescale ----
        float rmax[4];
#pragma unroll
        for (int r = 0; r < 4; r++) {
            float t0 = fmaxf(fmaxf(s[0][r], s[1][r]), fmaxf(s[2][r], s[3][r]));
            rmax[r] = rowmax16(t0);
        }
        bool grew = false;
#pragma unroll
        for (int r = 0; r < 4; r++) grew = grew || (rmax[r] > m_r[r]);
        if (__any((int)grew)) {
#pragma unroll
            for (int r = 0; r < 4; r++) {
                float mnew = fmaxf(m_r[r], rmax[r]);
                float al = exp2f(m_r[r] - mnew);   // exp2(-inf)=0 on first tile
                m_r[r] = mnew;
                acc_l[r] *= al;
#pragma unroll
                for (int t = 0; t < 4; t++) o_acc[t][r] *= al;
            }
        }

        // ---- P = exp2(s - m), store bf16 to wave-private LDS ----
#pragma unroll
        for (int n = 0; n < 4; n++) {
#pragma unroll
            for (int r = 0; r < 4; r++) {
                float p = exp2f(s[n][r] - m_r[r]);   // masked: exp2(-inf)=0
                Ps[w][(lgrp * 4 + r) * LSTR + n * 16 + lrow] = f2b(p);
            }
        }

        // ---- PV + row-sum: O += P*V ; acc_l += P*ones  (V^T swizzled) ----
        __builtin_amdgcn_s_setprio(1);
#pragma unroll
        for (int ks = 0; ks < 2; ks++) {
            bf16x8 pa = *(const bf16x8*)&Ps[w][lrow * LSTR + lgrp * 8 + ks * 32];
            acc_l = __builtin_amdgcn_mfma_f32_16x16x32_bf16(pa, ones, acc_l, 0, 0, 0);
#pragma unroll
            for (int t = 0; t < 4; t++) {
                const int xr = (2 * t + (lrow >> 3)) << 3;   // (d>>3)<<3, d = t*16+lrow
                bf16x8 vb = *(const bf16x8*)&Vs[(t * 16 + lrow) * LSTR + ((lgrp * 8 + ks * 32) ^ xr)];
                o_acc[t] = __builtin_amdgcn_mfma_f32_16x16x32_bf16(pa, vb, o_acc[t], 0, 0, 0);
            }
        }
        __builtin_amdgcn_s_setprio(0);
    }

    // ---- epilogue: normalize and store bf16 ----
    float invl[4];
#pragma unroll
    for (int r = 0; r < 4; r++) invl[r] = 1.0f / acc_l[r];
    ushort* op = O + (size_t)(qbase + w * 16) * DMODEL + h * DKH;
#pragma unroll
    for (int t = 0; t < 4; t++)
#pragma unroll
        for (int r = 0; r < 4; r++)
            op[(size_t)(lgrp * 4 + r) * DMODEL + t * 16 + lrow] = f2b(o_acc[t][r] * invl[r]);
}

// ---------------------------------------------------------------------------
extern "C" void kernel_launch(void* const* d_in, const int* in_sizes, int n_in,
                              void* d_out, int out_size, void* d_ws, size_t ws_size,
                              hipStream_t stream) {
    const float* x  = (const float*)d_in[0];
    const float* Wq = (const float*)d_in[1];
    const float* Wk = (const float*)d_in[2];
    const float* Wv = (const float*)d_in[3];
    const float* Wo = (const float*)d_in[4];
    float* out = (float*)d_out;

    const size_t NM = (size_t)SEQ * DMODEL;      // 4 M elems
    const size_t NW = (size_t)DMODEL * DMODEL;   // 1 M elems
    ushort* qb  = (ushort*)d_ws;                 // q,k,v contiguous (QKV-split out)
    ushort* kb  = qb + NM;
    ushort* vb  = kb + NM;
    ushort* ob  = vb + NM;
    ushort* xb  = ob + NM;
    ushort* wqb = xb + NM;                       // Wq,Wk,Wv contiguous (3072-row B)
    ushort* wkb = wqb + NW;
    ushort* wvb = wkb + NW;
    ushort* wob = wvb + NW;   // total 48 MB

    conv_bf16<<<8192, 256, 0, stream>>>(x, Wq, Wk, Wv, Wo, xb, wqb, wkb, wvb, wob);

    // fused QKV projection: B = [Wq;Wk;Wv] (3072x1024), 768 blocks = 3/CU
    gemm_bf16<2><<<dim3(3 * DMODEL / 128, SEQ / 128), 256, 0, stream>>>(
        xb, wqb, qb, SEQ, 3 * DMODEL, DMODEL);

    rope_bf16<<<SEQ * (DMODEL / 2) / 256, 256, 0, stream>>>(qb, kb);

    attn_mfma<<<dim3(SEQ / 64, NHEAD), 256, 0, stream>>>(qb, kb, vb, ob);

    gemm_bf16<0><<<dim3(DMODEL / 128, SEQ / 128), 256, 0, stream>>>(
        ob, wob, out, SEQ, DMODEL, DMODEL);
}